// Round 21
// baseline (141.950 us; speedup 1.0000x reference)
//
#include <hip/hip_runtime.h>
#include <hip/hip_bf16.h>

#define B_ 8
#define N_ 4096
#define D_ 512
#define K_ 64
#define QD_ 128

typedef float f32x4 __attribute__((ext_vector_type(4)));
typedef short short8 __attribute__((ext_vector_type(8)));
typedef unsigned short u16;
typedef unsigned int u32;

__device__ __forceinline__ u16 f2bf(float f) {
  u32 u = __float_as_uint(f);
  return (u16)((u + 0x7fffu + ((u >> 16) & 1u)) >> 16);
}
__device__ __forceinline__ float bf2f(u16 h) {
  return __uint_as_float((u32)h << 16);
}

__device__ __forceinline__ void load8f(const float* p, float* r) {
  float4 a = *(const float4*)(p);
  float4 b = *(const float4*)(p + 4);
  r[0] = a.x; r[1] = a.y; r[2] = a.z; r[3] = a.w;
  r[4] = b.x; r[5] = b.y; r[6] = b.z; r[7] = b.w;
}

__device__ __forceinline__ void store_comp(char* msgL, int row, int u, int s,
                                           int swz, const float* m) {
  uint4 val;
  val.x = (u32)f2bf(m[0]) | ((u32)f2bf(m[1]) << 16);
  val.y = (u32)f2bf(m[2]) | ((u32)f2bf(m[3]) << 16);
  val.z = (u32)f2bf(m[4]) | ((u32)f2bf(m[5]) << 16);
  val.w = (u32)f2bf(m[6]) | ((u32)f2bf(m[7]) << 16);
  const int byte = (row * 1024 + u * 256 + s * 16) ^ swz;
  *(uint4*)(msgL + byte) = val;
}

// ---------------------------------------------------------------------------
// K0: FUSED prep. [0,2048): weight expansion (both sets, fragment order);
// [2048,2176): densify A (thread owns column); [2176,2184): zero proto_raw;
// 2184: zero wsum. No fences, no cross-block communication.
// ---------------------------------------------------------------------------
__global__ __launch_bounds__(256) void k_prep(
    const float* __restrict__ uw, const float* __restrict__ pw,
    u16* __restrict__ uwf, u16* __restrict__ pwf,
    const int* __restrict__ aidx, const float* __restrict__ aw,
    const float* __restrict__ mask, u16* __restrict__ A,
    float* __restrict__ proto_raw, float* __restrict__ wsum) {
  if (blockIdx.x < 2048) {
    const int gid = blockIdx.x * 256 + threadIdx.x;  // < 2 * 2^18
    const int sel = gid >> 18;
    const int idx = gid & ((1 << 18) - 1);
    const int e = idx & 7;
    const int lane = (idx >> 3) & 63;
    const int ks = (idx >> 9) & 15;
    const int cf = idx >> 13;  // 0..31
    const int col = (cf >> 3) * 128 + (cf & 7) * 16 + (lane & 15);
    const int v = ks * 32 + (lane >> 4) * 8 + e;
    const int u = col >> 7, a = col & 127, c = v >> 7, bb = v & 127;
    const int   matT[4][4] = {{0,1,2,3},{1,0,3,2},{2,3,0,1},{3,2,1,0}};
    const float sgnT[4][4] = {{1.f,-1.f,-1.f,-1.f},{1.f,1.f,-1.f,1.f},
                              {1.f,1.f,1.f,-1.f},{1.f,-1.f,1.f,1.f}};
    const float* w4 = sel ? pw : uw;
    u16* dst = sel ? pwf : uwf;
    dst[idx] = f2bf(sgnT[u][c] * w4[matT[u][c] * QD_ * QD_ + a * QD_ + bb]);
  } else if (blockIdx.x < 2176) {
    const int gid = (blockIdx.x - 2048) * 256 + threadIdx.x;  // b*4096 + n
    const int b = gid >> 12, n = gid & 4095;
    const size_t ib = (size_t)gid * 3;
    const int k0 = aidx[ib], k1 = aidx[ib + 1], k2 = aidx[ib + 2];
    const float mk = mask[gid];
    float w0 = aw[ib] * mk, w1 = aw[ib + 1] * mk, w2 = aw[ib + 2] * mk;
    bool skip1 = false, skip2 = false;
    if (k1 == k0) { w0 += w1; skip1 = true; }
    if (k2 == k0) { w0 += w2; skip2 = true; }
    else if (k2 == k1 && !skip1) { w1 += w2; skip2 = true; }
    u16* Ab = A + (size_t)b * K_ * N_;
#pragma unroll
    for (int k = 0; k < K_; ++k) Ab[(size_t)k * N_ + n] = 0;
    Ab[(size_t)k0 * N_ + n] = f2bf(w0);
    if (!skip1) Ab[(size_t)k1 * N_ + n] = f2bf(w1);
    if (!skip2) Ab[(size_t)k2 * N_ + n] = f2bf(w2);
  } else if (blockIdx.x < 2184) {
    // zero proto_raw: 8 blocks x 128 KB
    float4 z = {0.f, 0.f, 0.f, 0.f};
    float4* dst = (float4*)proto_raw + (size_t)(blockIdx.x - 2176) * 8192;
    for (int i = threadIdx.x; i < 8192; i += 256) dst[i] = z;
  } else {
    // zero wsum (512 f32)
    float4 z = {0.f, 0.f, 0.f, 0.f};
    if (threadIdx.x < 128) ((float4*)wsum)[threadIdx.x] = z;
  }
}

// ---------------------------------------------------------------------------
// K1: proto_raw[b] = A[b] @ q[b] via bf16 MFMA; dq==0 blocks also fold in
// the wsum row-sum from L2-hot A. 512 blocks (1D, XCD-swizzled so XCD x
// owns batch x -> A[b] fully L2-resident); n-chunk = 256 rows (4 subs of 64).
// setprio(1) around the MFMA cluster (T5: helps when co-resident blocks are
// phase-staggered).
// ---------------------------------------------------------------------------
__global__ __launch_bounds__(256) void k_gemmA(
    const u16* __restrict__ A, const float* __restrict__ q,
    float* __restrict__ proto_raw, float* __restrict__ wsum) {
  __shared__ __align__(16) u16 Bt[128 * 64];  // [d'][n'] swizzled, 16 KB
  const int t = threadIdx.x;
  const int bid = blockIdx.x;                 // 0..511
  const int wg = (bid & 7) * 64 + (bid >> 3); // XCD x -> wg in [x*64, x*64+64)
  const int kc = wg & 15;                     // n-chunk of 256
  const int dq = (wg >> 4) & 3;               // 128-d quarter
  const int b = wg >> 6;                      // batch == XCD id
  const int n_base = kc * 256;
  const u16* Ab = A + (size_t)b * K_ * N_;
  const float* qb = q + ((size_t)b * N_ + n_base) * D_ + dq * 128;

  const int lane = t & 63, wv = t >> 6;
  const int g = lane >> 4, l16 = lane & 15;
  const int sn = t >> 2, sdq = (t & 3) * 32;  // staging map

  f32x4 acc[4][2];
#pragma unroll
  for (int mt = 0; mt < 4; ++mt)
#pragma unroll
    for (int nt = 0; nt < 2; ++nt) { f32x4 z = {0.f,0.f,0.f,0.f}; acc[mt][nt] = z; }

  float4 pre[8];
#pragma unroll
  for (int e = 0; e < 8; ++e)
    pre[e] = *(const float4*)(qb + (size_t)sn * D_ + sdq + e * 4);

  for (int sub = 0; sub < 4; ++sub) {
    __syncthreads();  // prev mfma done reading Bt
#pragma unroll
    for (int e = 0; e < 8; ++e) {
      const float4 v = pre[e];
#pragma unroll
      for (int x = 0; x < 4; ++x) {
        const int d = sdq + e * 4 + x;
        const float fv = (x == 0) ? v.x : (x == 1) ? v.y : (x == 2) ? v.z : v.w;
        const int byte = (d * 128 + sn * 2) ^ ((d & 7) << 4);
        *(u16*)((char*)Bt + byte) = f2bf(fv);
      }
    }
    float4 nxt[8];
    if (sub < 3) {
#pragma unroll
      for (int e = 0; e < 8; ++e)
        nxt[e] = *(const float4*)(qb + (size_t)((sub + 1) * 64 + sn) * D_ + sdq + e * 4);
    }
    __syncthreads();  // Bt writes visible
    const int n0 = n_base + sub * 64;
    __builtin_amdgcn_s_setprio(1);
#pragma unroll
    for (int ks = 0; ks < 2; ++ks) {
      short8 bfrag[2];
#pragma unroll
      for (int nt = 0; nt < 2; ++nt) {
        const int d = wv * 32 + nt * 16 + l16;
        const int byte = (d * 128 + (ks * 32 + g * 8) * 2) ^ ((d & 7) << 4);
        bfrag[nt] = *(const short8*)((const char*)Bt + byte);
      }
#pragma unroll
      for (int mt = 0; mt < 4; ++mt) {
        const short8 afr = *(const short8*)(Ab + (size_t)(mt * 16 + l16) * N_ +
                                            n0 + ks * 32 + g * 8);
#pragma unroll
        for (int nt = 0; nt < 2; ++nt)
          acc[mt][nt] = __builtin_amdgcn_mfma_f32_16x16x32_bf16(afr, bfrag[nt], acc[mt][nt], 0, 0, 0);
      }
    }
    __builtin_amdgcn_s_setprio(0);
#pragma unroll
    for (int e = 0; e < 8; ++e) pre[e] = nxt[e];
  }

#pragma unroll
  for (int mt = 0; mt < 4; ++mt)
#pragma unroll
    for (int nt = 0; nt < 2; ++nt)
#pragma unroll
      for (int rg = 0; rg < 4; ++rg) {
        const int code = mt * 16 + g * 4 + rg;
        const int d = dq * 128 + wv * 32 + nt * 16 + l16;
        atomicAdd(&proto_raw[((size_t)b * K_ + code) * D_ + d], acc[mt][nt][rg]);
      }

  // fused wsum partial: only the dq==0 slice; A tile is L2-hot here.
  if (dq == 0) {
    const int k = t >> 2, part = t & 3;  // 4 threads per k row
    const u16* ap = Ab + (size_t)k * N_ + n_base + part * 64;
    float s = 0.f;
#pragma unroll
    for (int i = 0; i < 8; ++i) {
      const short8 v = *(const short8*)(ap + i * 8);
#pragma unroll
      for (int e = 0; e < 8; ++e) s += bf2f((u16)v[e]);
    }
    s += __shfl_xor(s, 1);
    s += __shfl_xor(s, 2);
    if (part == 0) atomicAdd(&wsum[b * K_ + k], s);
  }
}

// ---------------------------------------------------------------------------
// K2: proto normalize + quaternion_linear via bf16 MFMA.
// ---------------------------------------------------------------------------
__global__ __launch_bounds__(256) void k_proto_mfma(
    const float* __restrict__ proto_raw, const float* __restrict__ wsum,
    const u16* __restrict__ pwf, const float* __restrict__ pb,
    float* __restrict__ proto_t, float* __restrict__ out_proto) {
  __shared__ __align__(16) u16 msgL[16 * 512];
  __shared__ float invs[16];
  const int t = threadIdx.x;
  const size_t R0 = (size_t)blockIdx.x * 16;
  if (t < 16) invs[t] = 1.f / (wsum[R0 + t] + 1e-6f);
  __syncthreads();

  {
    const int s = t & 15, row = t >> 4;  // row 0..15
    const float iv = invs[row];
    const float* base = proto_raw + (R0 + row) * D_;
    const int swz = (row & 7) << 4;
#pragma unroll
    for (int u = 0; u < 4; ++u) {
      float m[8];
      load8f(base + u * 128 + s * 8, m);
#pragma unroll
      for (int e = 0; e < 8; ++e) m[e] *= iv;
      store_comp((char*)msgL, row, u, s, swz, m);
    }
  }
  __syncthreads();

  const int lane = t & 63, wv = t >> 6;
  const int g = lane >> 4, l16 = lane & 15;
  f32x4 acc[8];
#pragma unroll
  for (int f = 0; f < 8; ++f) { f32x4 z = {0.f,0.f,0.f,0.f}; acc[f] = z; }
#pragma unroll 4
  for (int ks = 0; ks < 16; ++ks) {
    const int arow = l16;
    const short8 a = *(const short8*)((const char*)msgL +
        ((arow * 1024 + ks * 64 + g * 16) ^ ((arow & 7) << 4)));
#pragma unroll
    for (int f = 0; f < 8; ++f) {
      const short8 bv = *(const short8*)(pwf +
          ((size_t)((wv * 8 + f) * 16 + ks) * 64 + lane) * 8);
      acc[f] = __builtin_amdgcn_mfma_f32_16x16x32_bf16(a, bv, acc[f], 0, 0, 0);
    }
  }

#pragma unroll
  for (int f = 0; f < 8; ++f) {
    const int col = wv * 128 + f * 16 + l16;
    const float pbv = pb[col];
#pragma unroll
    for (int rg = 0; rg < 4; ++rg) {
      const size_t row = R0 + g * 4 + rg;
      const float v = acc[f][rg] + pbv;
      proto_t[row * D_ + col] = v;
      out_proto[row * D_ + col] = v;
    }
  }
}

// ---------------------------------------------------------------------------
// K3: fused routing + hamilton + upd linear (bf16 MFMA) + residual + quat-LN.
// 1024 blocks x 256 threads (4 waves); 32 rows/block; LDS 32 KB; plain
// __launch_bounds__(256). XCD-swizzled blockIdx: XCD x owns batch x ->
// proto_t gather working set 1 MB/XCD (L2-resident). setprio around MFMA;
// LN uses one-pass moments (var = E[x^2] - mean^2). Grid = 1024.
// ---------------------------------------------------------------------------
__global__ __launch_bounds__(256) void k_main8(
    const float* __restrict__ q, const int* __restrict__ aidx,
    const float* __restrict__ aw, const float* __restrict__ proto_t,
    const u16* __restrict__ uwf, const float* __restrict__ ub,
    const float* __restrict__ gamma, const float* __restrict__ beta,
    float* __restrict__ out_q) {
  __shared__ __align__(16) u16 msgL[32 * 512];  // 32 KB, XOR-swizzled
  const int t = threadIdx.x;
  const int bid = blockIdx.x;  // 1024
  const size_t R0 = (size_t)((bid & 7) * 128 + (bid >> 3)) * 32;  // XCD x -> batch x

  // ---- stage A: P-sum + single Hamilton -> bf16 swizzled LDS ----
  {
    const int s = t & 15, rowHalf = t >> 4;  // rowHalf 0..15
    int kks[2][3]; float wws[2][3];
#pragma unroll
    for (int p = 0; p < 2; ++p) {
      const size_t gr = R0 + p * 16 + rowHalf;
      const int* ip = aidx + gr * 3;
      const float* wp = aw + gr * 3;
#pragma unroll
      for (int j = 0; j < 3; ++j) { kks[p][j] = ip[j]; wws[p][j] = wp[j]; }
    }
#pragma unroll
    for (int p = 0; p < 2; ++p) {
      const int row = p * 16 + rowHalf;
      const size_t gr = R0 + row;
      const int b = (int)(gr >> 12);
      const float* qp = q + gr * D_ + s * 8;
      float qr_[8], qi_[8], qj_[8], qk_[8];
      load8f(qp, qr_); load8f(qp + 128, qi_);
      load8f(qp + 256, qj_); load8f(qp + 384, qk_);
      float Pr[8], Pi[8], Pj[8], Pk[8];
#pragma unroll
      for (int e = 0; e < 8; ++e) { Pr[e] = Pi[e] = Pj[e] = Pk[e] = 0.f; }
#pragma unroll
      for (int j = 0; j < 3; ++j) {
        const float w = wws[p][j];
        const float* pp = proto_t + (size_t)(b * K_ + kks[p][j]) * D_ + s * 8;
        float pr[8], pi[8], pj[8], pk[8];
        load8f(pp, pr); load8f(pp + 128, pi);
        load8f(pp + 256, pj); load8f(pp + 384, pk);
#pragma unroll
        for (int e = 0; e < 8; ++e) {
          Pr[e] += w * pr[e]; Pi[e] += w * pi[e];
          Pj[e] += w * pj[e]; Pk[e] += w * pk[e];
        }
      }
      const int swz = (row & 7) << 4;
      float m[8];
#pragma unroll
      for (int e = 0; e < 8; ++e)
        m[e] = qr_[e]*Pr[e] - qi_[e]*Pi[e] - qj_[e]*Pj[e] - qk_[e]*Pk[e];
      store_comp((char*)msgL, row, 0, s, swz, m);
#pragma unroll
      for (int e = 0; e < 8; ++e)
        m[e] = qr_[e]*Pi[e] + qi_[e]*Pr[e] + qj_[e]*Pk[e] - qk_[e]*Pj[e];
      store_comp((char*)msgL, row, 1, s, swz, m);
#pragma unroll
      for (int e = 0; e < 8; ++e)
        m[e] = qr_[e]*Pj[e] - qi_[e]*Pk[e] + qj_[e]*Pr[e] + qk_[e]*Pi[e];
      store_comp((char*)msgL, row, 2, s, swz, m);
#pragma unroll
      for (int e = 0; e < 8; ++e)
        m[e] = qr_[e]*Pk[e] + qi_[e]*Pj[e] - qj_[e]*Pi[e] + qk_[e]*Pr[e];
      store_comp((char*)msgL, row, 3, s, swz, m);
    }
  }
  __syncthreads();

  // ---- stage B: GEMM 32x512x512 via mfma_f32_16x16x32_bf16 ----
  const int lane = t & 63, c4 = t >> 6;  // wave = quaternion component
  const int g = lane >> 4, l16 = lane & 15;
  f32x4 acc[2][8];
#pragma unroll
  for (int st = 0; st < 2; ++st)
#pragma unroll
    for (int f = 0; f < 8; ++f) { f32x4 z = {0.f,0.f,0.f,0.f}; acc[st][f] = z; }
#pragma unroll 2
  for (int ks = 0; ks < 16; ++ks) {
    short8 bfr[8];
#pragma unroll
    for (int f = 0; f < 8; ++f)
      bfr[f] = *(const short8*)(uwf +
          ((size_t)((c4 * 8 + f) * 16 + ks) * 64 + lane) * 8);
    __builtin_amdgcn_s_setprio(1);
#pragma unroll
    for (int st = 0; st < 2; ++st) {
      const int arow = st * 16 + l16;
      const short8 a = *(const short8*)((const char*)msgL +
          ((arow * 1024 + ks * 64 + g * 16) ^ ((arow & 7) << 4)));
#pragma unroll
      for (int f = 0; f < 8; ++f)
        acc[st][f] = __builtin_amdgcn_mfma_f32_16x16x32_bf16(a, bfr[f], acc[st][f], 0, 0, 0);
    }
    __builtin_amdgcn_s_setprio(0);
  }

  // ---- epilogue: bias + residual folded into acc, then quat-LN ----
  const int colQ = c4 * 128;
#pragma unroll
  for (int st = 0; st < 2; ++st)
#pragma unroll
    for (int f = 0; f < 8; ++f) {
      const int col = colQ + f * 16 + l16;
      const float ubv = ub[col];
#pragma unroll
      for (int rg = 0; rg < 4; ++rg) {
        const size_t row = R0 + st * 16 + g * 4 + rg;
        acc[st][f][rg] += ubv + q[row * D_ + col];
      }
    }
#pragma unroll
  for (int st = 0; st < 2; ++st)
#pragma unroll
    for (int rg = 0; rg < 4; ++rg) {
      float s = 0.f, sq = 0.f;
#pragma unroll
      for (int f = 0; f < 8; ++f) {
        const float x = acc[st][f][rg];
        s += x; sq += x * x;
      }
      s  += __shfl_xor(s, 1);  s  += __shfl_xor(s, 2);
      s  += __shfl_xor(s, 4);  s  += __shfl_xor(s, 8);
      sq += __shfl_xor(sq, 1); sq += __shfl_xor(sq, 2);
      sq += __shfl_xor(sq, 4); sq += __shfl_xor(sq, 8);
      const float mean = s * 0.0078125f;
      const float var = sq * 0.0078125f - mean * mean;
      const float rstd = rsqrtf(var + 1e-5f);
      const size_t row = R0 + st * 16 + g * 4 + rg;
#pragma unroll
      for (int f = 0; f < 8; ++f) {
        const int col = colQ + f * 16 + l16;
        const float xn = (acc[st][f][rg] - mean) * rstd;
        out_q[row * D_ + col] = xn * gamma[col] + beta[col];
      }
    }
}

extern "C" void kernel_launch(void* const* d_in, const int* in_sizes, int n_in,
                              void* d_out, int out_size, void* d_ws, size_t ws_size,
                              hipStream_t stream) {
  const float* q     = (const float*)d_in[0];
  const int*   aidx  = (const int*)d_in[1];
  const float* aw    = (const float*)d_in[2];
  const float* mask  = (const float*)d_in[3];
  const float* pw    = (const float*)d_in[4];
  const float* pb    = (const float*)d_in[5];
  const float* uw    = (const float*)d_in[6];
  const float* ub    = (const float*)d_in[7];
  const float* gamma = (const float*)d_in[8];
  const float* beta  = (const float*)d_in[9];

  char* ws = (char*)d_ws;
  const size_t MB = 1 << 20;
  float* proto_raw = (float*)ws;                        // 1 MB
  float* wsum      = (float*)(ws + MB);                 // 2 KB (pad 4 KB)
  u16*   A         = (u16*)(ws + MB + 4096);            // 4 MB (zeroed in k_prep)
  float* proto_t   = (float*)(ws + 5 * MB + 4096);      // 1 MB
  u16*   uwf       = (u16*)(ws + 6 * MB + 4096);        // 512 KB
  u16*   pwf       = (u16*)(ws + 6 * MB + 4096 + (512 << 10)); // 512 KB

  float* out_q = (float*)d_out;                         // (B,N,D) f32
  float* out_proto = out_q + (size_t)B_ * N_ * D_;      // (B,K,D) f32

  k_prep<<<2185, 256, 0, stream>>>(uw, pw, uwf, pwf, aidx, aw, mask, A,
                                   proto_raw, wsum);
  k_gemmA<<<512, 256, 0, stream>>>(A, q, proto_raw, wsum);
  k_proto_mfma<<<32, 256, 0, stream>>>(proto_raw, wsum, pwf, pb, proto_t, out_proto);
  k_main8<<<1024, 256, 0, stream>>>(q, aidx, aw, proto_t, uwf, ub, gamma, beta, out_q);
}

// Round 22
// 121.762 us; speedup vs baseline: 1.1658x; 1.1658x over previous
//
#include <hip/hip_runtime.h>
#include <hip/hip_bf16.h>

#define B_ 8
#define N_ 4096
#define D_ 512
#define K_ 64
#define QD_ 128

typedef float f32x4 __attribute__((ext_vector_type(4)));
typedef short short8 __attribute__((ext_vector_type(8)));
typedef unsigned short u16;
typedef unsigned int u32;

__device__ __forceinline__ u16 f2bf(float f) {
  u32 u = __float_as_uint(f);
  return (u16)((u + 0x7fffu + ((u >> 16) & 1u)) >> 16);
}
__device__ __forceinline__ float bf2f(u16 h) {
  return __uint_as_float((u32)h << 16);
}

__device__ __forceinline__ void load8f(const float* p, float* r) {
  float4 a = *(const float4*)(p);
  float4 b = *(const float4*)(p + 4);
  r[0] = a.x; r[1] = a.y; r[2] = a.z; r[3] = a.w;
  r[4] = b.x; r[5] = b.y; r[6] = b.z; r[7] = b.w;
}

__device__ __forceinline__ void store_comp(char* msgL, int row, int u, int s,
                                           int swz, const float* m) {
  uint4 val;
  val.x = (u32)f2bf(m[0]) | ((u32)f2bf(m[1]) << 16);
  val.y = (u32)f2bf(m[2]) | ((u32)f2bf(m[3]) << 16);
  val.z = (u32)f2bf(m[4]) | ((u32)f2bf(m[5]) << 16);
  val.w = (u32)f2bf(m[6]) | ((u32)f2bf(m[7]) << 16);
  const int byte = (row * 1024 + u * 256 + s * 16) ^ swz;
  *(uint4*)(msgL + byte) = val;
}

// ---------------------------------------------------------------------------
// K0: FUSED prep. [0,2048): weight expansion (both sets, fragment order);
// [2048,2176): densify A (thread owns column); [2176,2184): zero proto_raw;
// 2184: zero wsum. No fences, no cross-block communication.
// ---------------------------------------------------------------------------
__global__ __launch_bounds__(256) void k_prep(
    const float* __restrict__ uw, const float* __restrict__ pw,
    u16* __restrict__ uwf, u16* __restrict__ pwf,
    const int* __restrict__ aidx, const float* __restrict__ aw,
    const float* __restrict__ mask, u16* __restrict__ A,
    float* __restrict__ proto_raw, float* __restrict__ wsum) {
  if (blockIdx.x < 2048) {
    const int gid = blockIdx.x * 256 + threadIdx.x;  // < 2 * 2^18
    const int sel = gid >> 18;
    const int idx = gid & ((1 << 18) - 1);
    const int e = idx & 7;
    const int lane = (idx >> 3) & 63;
    const int ks = (idx >> 9) & 15;
    const int cf = idx >> 13;  // 0..31
    const int col = (cf >> 3) * 128 + (cf & 7) * 16 + (lane & 15);
    const int v = ks * 32 + (lane >> 4) * 8 + e;
    const int u = col >> 7, a = col & 127, c = v >> 7, bb = v & 127;
    const int   matT[4][4] = {{0,1,2,3},{1,0,3,2},{2,3,0,1},{3,2,1,0}};
    const float sgnT[4][4] = {{1.f,-1.f,-1.f,-1.f},{1.f,1.f,-1.f,1.f},
                              {1.f,1.f,1.f,-1.f},{1.f,-1.f,1.f,1.f}};
    const float* w4 = sel ? pw : uw;
    u16* dst = sel ? pwf : uwf;
    dst[idx] = f2bf(sgnT[u][c] * w4[matT[u][c] * QD_ * QD_ + a * QD_ + bb]);
  } else if (blockIdx.x < 2176) {
    const int gid = (blockIdx.x - 2048) * 256 + threadIdx.x;  // b*4096 + n
    const int b = gid >> 12, n = gid & 4095;
    const size_t ib = (size_t)gid * 3;
    const int k0 = aidx[ib], k1 = aidx[ib + 1], k2 = aidx[ib + 2];
    const float mk = mask[gid];
    float w0 = aw[ib] * mk, w1 = aw[ib + 1] * mk, w2 = aw[ib + 2] * mk;
    bool skip1 = false, skip2 = false;
    if (k1 == k0) { w0 += w1; skip1 = true; }
    if (k2 == k0) { w0 += w2; skip2 = true; }
    else if (k2 == k1 && !skip1) { w1 += w2; skip2 = true; }
    u16* Ab = A + (size_t)b * K_ * N_;
#pragma unroll
    for (int k = 0; k < K_; ++k) Ab[(size_t)k * N_ + n] = 0;
    Ab[(size_t)k0 * N_ + n] = f2bf(w0);
    if (!skip1) Ab[(size_t)k1 * N_ + n] = f2bf(w1);
    if (!skip2) Ab[(size_t)k2 * N_ + n] = f2bf(w2);
  } else if (blockIdx.x < 2184) {
    // zero proto_raw: 8 blocks x 128 KB
    float4 z = {0.f, 0.f, 0.f, 0.f};
    float4* dst = (float4*)proto_raw + (size_t)(blockIdx.x - 2176) * 8192;
    for (int i = threadIdx.x; i < 8192; i += 256) dst[i] = z;
  } else {
    // zero wsum (512 f32)
    float4 z = {0.f, 0.f, 0.f, 0.f};
    if (threadIdx.x < 128) ((float4*)wsum)[threadIdx.x] = z;
  }
}

// ---------------------------------------------------------------------------
// K1: proto_raw[b] = A[b] @ q[b] via bf16 MFMA; dq==0 blocks also fold in
// the wsum row-sum from L2-hot A. 512 blocks (1D, XCD-swizzled so XCD x
// owns batch x -> A[b] fully L2-resident); n-chunk = 256 rows (4 subs of 64).
// ---------------------------------------------------------------------------
__global__ __launch_bounds__(256) void k_gemmA(
    const u16* __restrict__ A, const float* __restrict__ q,
    float* __restrict__ proto_raw, float* __restrict__ wsum) {
  __shared__ __align__(16) u16 Bt[128 * 64];  // [d'][n'] swizzled, 16 KB
  const int t = threadIdx.x;
  const int bid = blockIdx.x;                 // 0..511
  const int wg = (bid & 7) * 64 + (bid >> 3); // XCD x -> wg in [x*64, x*64+64)
  const int kc = wg & 15;                     // n-chunk of 256
  const int dq = (wg >> 4) & 3;               // 128-d quarter
  const int b = wg >> 6;                      // batch == XCD id
  const int n_base = kc * 256;
  const u16* Ab = A + (size_t)b * K_ * N_;
  const float* qb = q + ((size_t)b * N_ + n_base) * D_ + dq * 128;

  const int lane = t & 63, wv = t >> 6;
  const int g = lane >> 4, l16 = lane & 15;
  const int sn = t >> 2, sdq = (t & 3) * 32;  // staging map

  f32x4 acc[4][2];
#pragma unroll
  for (int mt = 0; mt < 4; ++mt)
#pragma unroll
    for (int nt = 0; nt < 2; ++nt) { f32x4 z = {0.f,0.f,0.f,0.f}; acc[mt][nt] = z; }

  float4 pre[8];
#pragma unroll
  for (int e = 0; e < 8; ++e)
    pre[e] = *(const float4*)(qb + (size_t)sn * D_ + sdq + e * 4);

  for (int sub = 0; sub < 4; ++sub) {
    __syncthreads();  // prev mfma done reading Bt
#pragma unroll
    for (int e = 0; e < 8; ++e) {
      const float4 v = pre[e];
#pragma unroll
      for (int x = 0; x < 4; ++x) {
        const int d = sdq + e * 4 + x;
        const float fv = (x == 0) ? v.x : (x == 1) ? v.y : (x == 2) ? v.z : v.w;
        const int byte = (d * 128 + sn * 2) ^ ((d & 7) << 4);
        *(u16*)((char*)Bt + byte) = f2bf(fv);
      }
    }
    float4 nxt[8];
    if (sub < 3) {
#pragma unroll
      for (int e = 0; e < 8; ++e)
        nxt[e] = *(const float4*)(qb + (size_t)((sub + 1) * 64 + sn) * D_ + sdq + e * 4);
    }
    __syncthreads();  // Bt writes visible
    const int n0 = n_base + sub * 64;
#pragma unroll
    for (int ks = 0; ks < 2; ++ks) {
      short8 bfrag[2];
#pragma unroll
      for (int nt = 0; nt < 2; ++nt) {
        const int d = wv * 32 + nt * 16 + l16;
        const int byte = (d * 128 + (ks * 32 + g * 8) * 2) ^ ((d & 7) << 4);
        bfrag[nt] = *(const short8*)((const char*)Bt + byte);
      }
#pragma unroll
      for (int mt = 0; mt < 4; ++mt) {
        const short8 afr = *(const short8*)(Ab + (size_t)(mt * 16 + l16) * N_ +
                                            n0 + ks * 32 + g * 8);
#pragma unroll
        for (int nt = 0; nt < 2; ++nt)
          acc[mt][nt] = __builtin_amdgcn_mfma_f32_16x16x32_bf16(afr, bfrag[nt], acc[mt][nt], 0, 0, 0);
      }
    }
#pragma unroll
    for (int e = 0; e < 8; ++e) pre[e] = nxt[e];
  }

#pragma unroll
  for (int mt = 0; mt < 4; ++mt)
#pragma unroll
    for (int nt = 0; nt < 2; ++nt)
#pragma unroll
      for (int rg = 0; rg < 4; ++rg) {
        const int code = mt * 16 + g * 4 + rg;
        const int d = dq * 128 + wv * 32 + nt * 16 + l16;
        atomicAdd(&proto_raw[((size_t)b * K_ + code) * D_ + d], acc[mt][nt][rg]);
      }

  // fused wsum partial: only the dq==0 slice; A tile is L2-hot here.
  if (dq == 0) {
    const int k = t >> 2, part = t & 3;  // 4 threads per k row
    const u16* ap = Ab + (size_t)k * N_ + n_base + part * 64;
    float s = 0.f;
#pragma unroll
    for (int i = 0; i < 8; ++i) {
      const short8 v = *(const short8*)(ap + i * 8);
#pragma unroll
      for (int e = 0; e < 8; ++e) s += bf2f((u16)v[e]);
    }
    s += __shfl_xor(s, 1);
    s += __shfl_xor(s, 2);
    if (part == 0) atomicAdd(&wsum[b * K_ + k], s);
  }
}

// ---------------------------------------------------------------------------
// K2: proto normalize + quaternion_linear via bf16 MFMA.
// ---------------------------------------------------------------------------
__global__ __launch_bounds__(256) void k_proto_mfma(
    const float* __restrict__ proto_raw, const float* __restrict__ wsum,
    const u16* __restrict__ pwf, const float* __restrict__ pb,
    float* __restrict__ proto_t, float* __restrict__ out_proto) {
  __shared__ __align__(16) u16 msgL[16 * 512];
  __shared__ float invs[16];
  const int t = threadIdx.x;
  const size_t R0 = (size_t)blockIdx.x * 16;
  if (t < 16) invs[t] = 1.f / (wsum[R0 + t] + 1e-6f);
  __syncthreads();

  {
    const int s = t & 15, row = t >> 4;  // row 0..15
    const float iv = invs[row];
    const float* base = proto_raw + (R0 + row) * D_;
    const int swz = (row & 7) << 4;
#pragma unroll
    for (int u = 0; u < 4; ++u) {
      float m[8];
      load8f(base + u * 128 + s * 8, m);
#pragma unroll
      for (int e = 0; e < 8; ++e) m[e] *= iv;
      store_comp((char*)msgL, row, u, s, swz, m);
    }
  }
  __syncthreads();

  const int lane = t & 63, wv = t >> 6;
  const int g = lane >> 4, l16 = lane & 15;
  f32x4 acc[8];
#pragma unroll
  for (int f = 0; f < 8; ++f) { f32x4 z = {0.f,0.f,0.f,0.f}; acc[f] = z; }
#pragma unroll 4
  for (int ks = 0; ks < 16; ++ks) {
    const int arow = l16;
    const short8 a = *(const short8*)((const char*)msgL +
        ((arow * 1024 + ks * 64 + g * 16) ^ ((arow & 7) << 4)));
#pragma unroll
    for (int f = 0; f < 8; ++f) {
      const short8 bv = *(const short8*)(pwf +
          ((size_t)((wv * 8 + f) * 16 + ks) * 64 + lane) * 8);
      acc[f] = __builtin_amdgcn_mfma_f32_16x16x32_bf16(a, bv, acc[f], 0, 0, 0);
    }
  }

#pragma unroll
  for (int f = 0; f < 8; ++f) {
    const int col = wv * 128 + f * 16 + l16;
    const float pbv = pb[col];
#pragma unroll
    for (int rg = 0; rg < 4; ++rg) {
      const size_t row = R0 + g * 4 + rg;
      const float v = acc[f][rg] + pbv;
      proto_t[row * D_ + col] = v;
      out_proto[row * D_ + col] = v;
    }
  }
}

// ---------------------------------------------------------------------------
// K3: fused routing + hamilton + upd linear (bf16 MFMA) + residual + quat-LN.
// 1024 blocks x 256 threads (4 waves); 32 rows/block; LDS 32 KB; plain
// __launch_bounds__(256). XCD-swizzled blockIdx: XCD x owns batch x ->
// proto_t gather working set 1 MB/XCD (L2-resident). Grid = 1024.
// VGPR 124 (4 regs under the 128 cliff) -- do NOT add register pressure:
// round-21's setprio + one-pass-LN pushed it to 132 -> 3 waves/SIMD -> 74us.
// ---------------------------------------------------------------------------
__global__ __launch_bounds__(256) void k_main8(
    const float* __restrict__ q, const int* __restrict__ aidx,
    const float* __restrict__ aw, const float* __restrict__ proto_t,
    const u16* __restrict__ uwf, const float* __restrict__ ub,
    const float* __restrict__ gamma, const float* __restrict__ beta,
    float* __restrict__ out_q) {
  __shared__ __align__(16) u16 msgL[32 * 512];  // 32 KB, XOR-swizzled
  const int t = threadIdx.x;
  const int bid = blockIdx.x;  // 1024
  const size_t R0 = (size_t)((bid & 7) * 128 + (bid >> 3)) * 32;  // XCD x -> batch x

  // ---- stage A: P-sum + single Hamilton -> bf16 swizzled LDS ----
  {
    const int s = t & 15, rowHalf = t >> 4;  // rowHalf 0..15
    int kks[2][3]; float wws[2][3];
#pragma unroll
    for (int p = 0; p < 2; ++p) {
      const size_t gr = R0 + p * 16 + rowHalf;
      const int* ip = aidx + gr * 3;
      const float* wp = aw + gr * 3;
#pragma unroll
      for (int j = 0; j < 3; ++j) { kks[p][j] = ip[j]; wws[p][j] = wp[j]; }
    }
#pragma unroll
    for (int p = 0; p < 2; ++p) {
      const int row = p * 16 + rowHalf;
      const size_t gr = R0 + row;
      const int b = (int)(gr >> 12);
      const float* qp = q + gr * D_ + s * 8;
      float qr_[8], qi_[8], qj_[8], qk_[8];
      load8f(qp, qr_); load8f(qp + 128, qi_);
      load8f(qp + 256, qj_); load8f(qp + 384, qk_);
      float Pr[8], Pi[8], Pj[8], Pk[8];
#pragma unroll
      for (int e = 0; e < 8; ++e) { Pr[e] = Pi[e] = Pj[e] = Pk[e] = 0.f; }
#pragma unroll
      for (int j = 0; j < 3; ++j) {
        const float w = wws[p][j];
        const float* pp = proto_t + (size_t)(b * K_ + kks[p][j]) * D_ + s * 8;
        float pr[8], pi[8], pj[8], pk[8];
        load8f(pp, pr); load8f(pp + 128, pi);
        load8f(pp + 256, pj); load8f(pp + 384, pk);
#pragma unroll
        for (int e = 0; e < 8; ++e) {
          Pr[e] += w * pr[e]; Pi[e] += w * pi[e];
          Pj[e] += w * pj[e]; Pk[e] += w * pk[e];
        }
      }
      const int swz = (row & 7) << 4;
      float m[8];
#pragma unroll
      for (int e = 0; e < 8; ++e)
        m[e] = qr_[e]*Pr[e] - qi_[e]*Pi[e] - qj_[e]*Pj[e] - qk_[e]*Pk[e];
      store_comp((char*)msgL, row, 0, s, swz, m);
#pragma unroll
      for (int e = 0; e < 8; ++e)
        m[e] = qr_[e]*Pi[e] + qi_[e]*Pr[e] + qj_[e]*Pk[e] - qk_[e]*Pj[e];
      store_comp((char*)msgL, row, 1, s, swz, m);
#pragma unroll
      for (int e = 0; e < 8; ++e)
        m[e] = qr_[e]*Pj[e] - qi_[e]*Pk[e] + qj_[e]*Pr[e] + qk_[e]*Pi[e];
      store_comp((char*)msgL, row, 2, s, swz, m);
#pragma unroll
      for (int e = 0; e < 8; ++e)
        m[e] = qr_[e]*Pk[e] + qi_[e]*Pj[e] - qj_[e]*Pi[e] + qk_[e]*Pr[e];
      store_comp((char*)msgL, row, 3, s, swz, m);
    }
  }
  __syncthreads();

  // ---- stage B: GEMM 32x512x512 via mfma_f32_16x16x32_bf16 ----
  const int lane = t & 63, c4 = t >> 6;  // wave = quaternion component
  const int g = lane >> 4, l16 = lane & 15;
  f32x4 acc[2][8];
#pragma unroll
  for (int st = 0; st < 2; ++st)
#pragma unroll
    for (int f = 0; f < 8; ++f) { f32x4 z = {0.f,0.f,0.f,0.f}; acc[st][f] = z; }
#pragma unroll 2
  for (int ks = 0; ks < 16; ++ks) {
    short8 bfr[8];
#pragma unroll
    for (int f = 0; f < 8; ++f)
      bfr[f] = *(const short8*)(uwf +
          ((size_t)((c4 * 8 + f) * 16 + ks) * 64 + lane) * 8);
#pragma unroll
    for (int st = 0; st < 2; ++st) {
      const int arow = st * 16 + l16;
      const short8 a = *(const short8*)((const char*)msgL +
          ((arow * 1024 + ks * 64 + g * 16) ^ ((arow & 7) << 4)));
#pragma unroll
      for (int f = 0; f < 8; ++f)
        acc[st][f] = __builtin_amdgcn_mfma_f32_16x16x32_bf16(a, bfr[f], acc[st][f], 0, 0, 0);
    }
  }

  // ---- epilogue: bias + residual folded into acc, then quat-LN ----
  const int colQ = c4 * 128;
#pragma unroll
  for (int st = 0; st < 2; ++st)
#pragma unroll
    for (int f = 0; f < 8; ++f) {
      const int col = colQ + f * 16 + l16;
      const float ubv = ub[col];
#pragma unroll
      for (int rg = 0; rg < 4; ++rg) {
        const size_t row = R0 + st * 16 + g * 4 + rg;
        acc[st][f][rg] += ubv + q[row * D_ + col];
      }
    }
#pragma unroll
  for (int st = 0; st < 2; ++st)
#pragma unroll
    for (int rg = 0; rg < 4; ++rg) {
      float s = 0.f;
#pragma unroll
      for (int f = 0; f < 8; ++f) s += acc[st][f][rg];
      s += __shfl_xor(s, 1); s += __shfl_xor(s, 2);
      s += __shfl_xor(s, 4); s += __shfl_xor(s, 8);
      const float mean = s * 0.0078125f;
      float sq = 0.f;
#pragma unroll
      for (int f = 0; f < 8; ++f) {
        const float d = acc[st][f][rg] - mean; sq += d * d;
      }
      sq += __shfl_xor(sq, 1); sq += __shfl_xor(sq, 2);
      sq += __shfl_xor(sq, 4); sq += __shfl_xor(sq, 8);
      const float rstd = rsqrtf(sq * 0.0078125f + 1e-5f);
      const size_t row = R0 + st * 16 + g * 4 + rg;
#pragma unroll
      for (int f = 0; f < 8; ++f) {
        const int col = colQ + f * 16 + l16;
        const float xn = (acc[st][f][rg] - mean) * rstd;
        out_q[row * D_ + col] = xn * gamma[col] + beta[col];
      }
    }
}

extern "C" void kernel_launch(void* const* d_in, const int* in_sizes, int n_in,
                              void* d_out, int out_size, void* d_ws, size_t ws_size,
                              hipStream_t stream) {
  const float* q     = (const float*)d_in[0];
  const int*   aidx  = (const int*)d_in[1];
  const float* aw    = (const float*)d_in[2];
  const float* mask  = (const float*)d_in[3];
  const float* pw    = (const float*)d_in[4];
  const float* pb    = (const float*)d_in[5];
  const float* uw    = (const float*)d_in[6];
  const float* ub    = (const float*)d_in[7];
  const float* gamma = (const float*)d_in[8];
  const float* beta  = (const float*)d_in[9];

  char* ws = (char*)d_ws;
  const size_t MB = 1 << 20;
  float* proto_raw = (float*)ws;                        // 1 MB
  float* wsum      = (float*)(ws + MB);                 // 2 KB (pad 4 KB)
  u16*   A         = (u16*)(ws + MB + 4096);            // 4 MB (zeroed in k_prep)
  float* proto_t   = (float*)(ws + 5 * MB + 4096);      // 1 MB
  u16*   uwf       = (u16*)(ws + 6 * MB + 4096);        // 512 KB
  u16*   pwf       = (u16*)(ws + 6 * MB + 4096 + (512 << 10)); // 512 KB

  float* out_q = (float*)d_out;                         // (B,N,D) f32
  float* out_proto = out_q + (size_t)B_ * N_ * D_;      // (B,K,D) f32

  k_prep<<<2185, 256, 0, stream>>>(uw, pw, uwf, pwf, aidx, aw, mask, A,
                                   proto_raw, wsum);
  k_gemmA<<<512, 256, 0, stream>>>(A, q, proto_raw, wsum);
  k_proto_mfma<<<32, 256, 0, stream>>>(proto_raw, wsum, pwf, pb, proto_t, out_proto);
  k_main8<<<1024, 256, 0, stream>>>(q, aidx, aw, proto_t, uwf, ub, gamma, beta, out_q);
}